// Round 5
// baseline (74.473 us; speedup 1.0000x reference)
//
#include <hip/hip_runtime.h>
#include <math.h>

// SSIM 1D loss: B=16, C=32, T=48000, window=11, sigma=1.5, zero padding.
// u/v reformulation: u=p+t, v=p-t =>
//   conv(u)=mu1+mu2, conv(v)=mu1-mu2, conv(u^2)=s11+2s12+s22, conv(v^2)=s11-2s12+s22
// => 4 depthwise convs, 2 squares/elem.
//
// R5: consume-on-load. R1-R4 all plateaued at ~70us with VGPR=32..40: hipcc's
// occupancy-maximizing scheduler refuses a large live set and turns "window in
// registers" into per-tap LDS/global re-reads. Here each loaded element is
// folded into the 16 accumulators IMMEDIATELY (k-major), so the live set is
// ~35 floats by construction and there is nothing to rematerialize.
constexpr int T     = 48000;
constexpr int TPB   = 256;
constexpr int OPT   = 4;            // outputs per thread
constexpr int TPROW = T / OPT;      // 12000 threads per row (exact)
constexpr float C1f = 0.0001f;      // 0.01^2
constexpr float C2f = 0.0009f;      // 0.03^2

struct W11 { float w[11]; };

__global__ __launch_bounds__(TPB) void ssim_main(
    const float* __restrict__ pred, const float* __restrict__ targ,
    float* __restrict__ partial, W11 wts)
{
    const int tid = blockIdx.x * TPB + (int)threadIdx.x;   // grid is exact: no guard
    const int row = tid / TPROW;                           // magic-mul
    const int pos = (tid - row * TPROW) * OPT;             // first output in row
    const float* pr = pred + (size_t)row * T;
    const float* tr = targ + (size_t)row * T;
    const int g0 = pos - 8;                                // 16B-aligned window start

    // accumulators: ca=conv(u), cb=conv(v), cc=conv(u^2), cd=conv(v^2)
    float ca[OPT] = {}, cb[OPT] = {}, cc[OPT] = {}, cd[OPT] = {};

    // element i (0..19) = x[g0+4j+c]; output m uses elements m+3..m+13 with
    // tap k = i-3-m. Fold each element into all its accumulators immediately.
    auto consume = [&](int j, const float4& a, const float4& b) {
        const float ae[4] = {a.x, a.y, a.z, a.w};
        const float be[4] = {b.x, b.y, b.z, b.w};
        #pragma unroll
        for (int c = 0; c < 4; c++) {
            const int i = 4 * j + c;
            if (i < 3 || i > 16) continue;                 // unused edges of the 5 quads
            const float u  = ae[c] + be[c];
            const float v  = ae[c] - be[c];
            const float uu = u * u;
            const float vv = v * v;
            #pragma unroll
            for (int m = 0; m < OPT; m++) {
                const int k = i - 3 - m;
                if (k < 0 || k > 10) continue;
                const float wk = wts.w[k];                 // SGPR, compile-time index
                ca[m] = fmaf(wk, u,  ca[m]);
                cb[m] = fmaf(wk, v,  cb[m]);
                cc[m] = fmaf(wk, uu, cc[m]);
                cd[m] = fmaf(wk, vv, cd[m]);
            }
        }
    };

    if (pos >= 8 && pos <= T - 12) {                       // interior: straight-line
        const float4* P4 = reinterpret_cast<const float4*>(pr + g0);
        const float4* Q4 = reinterpret_cast<const float4*>(tr + g0);
        #pragma unroll
        for (int j = 0; j < 5; j++) consume(j, P4[j], Q4[j]);
    } else {                                               // 4 threads/row: zero-fill OOB
        #pragma unroll
        for (int j = 0; j < 5; j++) {
            const int q = g0 + 4 * j;                      // quad fully in or out (T%4==0)
            float4 a = {0.f,0.f,0.f,0.f}, b = {0.f,0.f,0.f,0.f};
            if (q >= 0 && q + 4 <= T) {
                a = *reinterpret_cast<const float4*>(pr + q);
                b = *reinterpret_cast<const float4*>(tr + q);
            }
            consume(j, a, b);
        }
    }

    // ---- SSIM epilogue; all OPT outputs in-bounds by construction ----
    float qsum = 0.f;
    #pragma unroll
    for (int m = 0; m < OPT; m++) {
        const float aa = ca[m] * ca[m], bb = cb[m] * cb[m];
        const float e  = 0.5f * (aa - bb);                 // 2*mu1*mu2
        const float f  = 0.5f * (aa + bb);                 // mu1^2+mu2^2
        const float t2 = 0.5f * (cc[m] - cd[m]);           // 2*s12
        const float sP = 0.5f * (cc[m] + cd[m]);           // s11+s22
        const float num = (e + C1f) * (t2 - e + C2f);
        const float den = (f + C1f) * (sP - f + C2f);
        qsum += num * __builtin_amdgcn_rcpf(den);          // den >= C1*C2 > 0
    }

    // ---- block reduction -> one partial per block ----
    #pragma unroll
    for (int off = 32; off; off >>= 1) qsum += __shfl_down(qsum, off);
    __shared__ float wsum[TPB / 64];
    if ((threadIdx.x & 63) == 0) wsum[threadIdx.x >> 6] = qsum;
    __syncthreads();
    if (threadIdx.x == 0) {
        float s = 0.f;
        #pragma unroll
        for (int i = 0; i < TPB / 64; i++) s += wsum[i];
        partial[blockIdx.x] = s;
    }
}

__global__ __launch_bounds__(256) void ssim_reduce(
    const float4* __restrict__ partial4, int n4, float* __restrict__ out, float inv_n)
{
    float s = 0.f;
    for (int i = threadIdx.x; i < n4; i += 256) {
        const float4 p = partial4[i];
        s += (p.x + p.y) + (p.z + p.w);
    }
    #pragma unroll
    for (int off = 32; off; off >>= 1) s += __shfl_down(s, off);
    __shared__ float ws[4];
    if ((threadIdx.x & 63) == 0) ws[threadIdx.x >> 6] = s;
    __syncthreads();
    if (threadIdx.x == 0) {
        float t = 0.f;
        #pragma unroll
        for (int i = 0; i < 4; i++) t += ws[i];
        out[0] = 1.f - t * inv_n;                          // mean(1-ssim) = 1 - mean(ssim)
    }
}

extern "C" void kernel_launch(void* const* d_in, const int* in_sizes, int n_in,
                              void* d_out, int out_size, void* d_ws, size_t ws_size,
                              hipStream_t stream)
{
    const float* pred = (const float*)d_in[0];
    const float* targ = (const float*)d_in[1];
    float* out = (float*)d_out;
    float* partial = (float*)d_ws;

    const int n        = in_sizes[0];                      // B*C*T = 24,576,000
    const int rows     = n / T;                            // 512
    const int nthreads = rows * TPROW;                     // 6,144,000 = 24000*256 exactly
    const int blocks   = nthreads / TPB;                   // 24,000 (96 KB of d_ws)

    // Gaussian window computed on host in double (matches numpy), cast to f32.
    W11 wts;
    double g[11], s = 0.0;
    for (int i = 0; i < 11; i++) { g[i] = exp(-((i - 5) * (i - 5)) / 4.5); s += g[i]; }
    for (int i = 0; i < 11; i++) wts.w[i] = (float)(g[i] / s);

    hipLaunchKernelGGL(ssim_main, dim3(blocks), dim3(TPB), 0, stream,
                       pred, targ, partial, wts);
    hipLaunchKernelGGL(ssim_reduce, dim3(1), dim3(256), 0, stream,
                       (const float4*)partial, blocks / 4, out, 1.0f / (float)n);
}

// Round 6
// 65.609 us; speedup vs baseline: 1.1351x; 1.1351x over previous
//
#include <hip/hip_runtime.h>
#include <math.h>

// SSIM 1D loss: B=16, C=32, T=48000, window=11, sigma=1.5, zero padding.
// u/v reformulation: u=p+t, v=p-t =>
//   conv(u)=mu1+mu2, conv(v)=mu1-mu2, conv(u^2)=s11+2s12+s22, conv(v^2)=s11-2s12+s22
// => 4 depthwise convs, 2 squares/elem.
//
// R6: consume-on-load (R5 dataflow, allocator-friendly live set) with OPT=8:
// halves vmem instr count (12/thread) and L1 redundancy (3x vs 5x), amortizes
// per-thread fixed overhead (div, epilogue, reduction) over 2x outputs.
constexpr int T     = 48000;
constexpr int TPB   = 256;
constexpr int OPT   = 8;            // outputs per thread
constexpr int TPROW = T / OPT;      // 6000 threads per row (exact)
constexpr float C1f = 0.0001f;      // 0.01^2
constexpr float C2f = 0.0009f;      // 0.03^2

struct W11 { float w[11]; };

__global__ __launch_bounds__(TPB, 4) void ssim_main(
    const float* __restrict__ pred, const float* __restrict__ targ,
    float* __restrict__ partial, W11 wts)
{
    const int tid = blockIdx.x * TPB + (int)threadIdx.x;   // grid exact: no guard
    const int row = tid / TPROW;                           // magic-mul
    const int pos = (tid - row * TPROW) * OPT;             // first output in row
    const float* pr = pred + (size_t)row * T;
    const float* tr = targ + (size_t)row * T;
    const int g0 = pos - 8;                                // 16B-aligned staged start

    // accumulators: ca=conv(u), cb=conv(v), cc=conv(u^2), cd=conv(v^2)
    float ca[OPT] = {}, cb[OPT] = {}, cc[OPT] = {}, cd[OPT] = {};

    // staged index i in [0,24) = x[g0+i]; output m uses staged [m+3 .. m+13]
    // (tap k = i-3-m in [0,10]); used i-range is [3,20].
    auto consume = [&](int j, const float4& a, const float4& b) {
        const float ae[4] = {a.x, a.y, a.z, a.w};
        const float be[4] = {b.x, b.y, b.z, b.w};
        #pragma unroll
        for (int c = 0; c < 4; c++) {
            const int i = 4 * j + c;
            if (i < 3 || i > 20) continue;
            const float u  = ae[c] + be[c];
            const float v  = ae[c] - be[c];
            const float uu = u * u;
            const float vv = v * v;
            #pragma unroll
            for (int m = 0; m < OPT; m++) {
                const int k = i - 3 - m;
                if (k < 0 || k > 10) continue;
                const float wk = wts.w[k];                 // SGPR, compile-time index
                ca[m] = fmaf(wk, u,  ca[m]);
                cb[m] = fmaf(wk, v,  cb[m]);
                cc[m] = fmaf(wk, uu, cc[m]);
                cd[m] = fmaf(wk, vv, cd[m]);
            }
        }
    };

    if (pos >= 8 && pos + 16 <= T) {                       // interior: straight-line
        const float4* P4 = reinterpret_cast<const float4*>(pr + g0);
        const float4* Q4 = reinterpret_cast<const float4*>(tr + g0);
        float4 pq[6], tq[6];
        #pragma unroll
        for (int j = 0; j < 6; j++) { pq[j] = P4[j]; tq[j] = Q4[j]; }   // MLP: all 12 in flight
        #pragma unroll
        for (int j = 0; j < 6; j++) consume(j, pq[j], tq[j]);
    } else {                                               // 2 threads/row: zero-fill OOB
        #pragma unroll
        for (int j = 0; j < 6; j++) {
            const int q = g0 + 4 * j;                      // quad fully in or out (T%4==0)
            float4 a = {0.f,0.f,0.f,0.f}, b = {0.f,0.f,0.f,0.f};
            if (q >= 0 && q + 4 <= T) {
                a = *reinterpret_cast<const float4*>(pr + q);
                b = *reinterpret_cast<const float4*>(tr + q);
            }
            consume(j, a, b);
        }
    }

    // ---- SSIM epilogue; all OPT outputs in-bounds by construction ----
    float qsum = 0.f;
    #pragma unroll
    for (int m = 0; m < OPT; m++) {
        const float aa = ca[m] * ca[m], bb = cb[m] * cb[m];
        const float e  = 0.5f * (aa - bb);                 // 2*mu1*mu2
        const float f  = 0.5f * (aa + bb);                 // mu1^2+mu2^2
        const float t2 = 0.5f * (cc[m] - cd[m]);           // 2*s12
        const float sP = 0.5f * (cc[m] + cd[m]);           // s11+s22
        const float num = (e + C1f) * (t2 - e + C2f);
        const float den = (f + C1f) * (sP - f + C2f);
        qsum += num * __builtin_amdgcn_rcpf(den);          // den >= C1*C2 > 0
    }

    // ---- block reduction -> one partial per block ----
    #pragma unroll
    for (int off = 32; off; off >>= 1) qsum += __shfl_down(qsum, off);
    __shared__ float wsum[TPB / 64];
    if ((threadIdx.x & 63) == 0) wsum[threadIdx.x >> 6] = qsum;
    __syncthreads();
    if (threadIdx.x == 0) {
        float s = 0.f;
        #pragma unroll
        for (int i = 0; i < TPB / 64; i++) s += wsum[i];
        partial[blockIdx.x] = s;
    }
}

__global__ __launch_bounds__(256) void ssim_reduce(
    const float4* __restrict__ partial4, int n4, float* __restrict__ out, float inv_n)
{
    float s = 0.f;
    for (int i = threadIdx.x; i < n4; i += 256) {
        const float4 p = partial4[i];
        s += (p.x + p.y) + (p.z + p.w);
    }
    #pragma unroll
    for (int off = 32; off; off >>= 1) s += __shfl_down(s, off);
    __shared__ float ws[4];
    if ((threadIdx.x & 63) == 0) ws[threadIdx.x >> 6] = s;
    __syncthreads();
    if (threadIdx.x == 0) {
        float t = 0.f;
        #pragma unroll
        for (int i = 0; i < 4; i++) t += ws[i];
        out[0] = 1.f - t * inv_n;                          // mean(1-ssim) = 1 - mean(ssim)
    }
}

extern "C" void kernel_launch(void* const* d_in, const int* in_sizes, int n_in,
                              void* d_out, int out_size, void* d_ws, size_t ws_size,
                              hipStream_t stream)
{
    const float* pred = (const float*)d_in[0];
    const float* targ = (const float*)d_in[1];
    float* out = (float*)d_out;
    float* partial = (float*)d_ws;

    const int n        = in_sizes[0];                      // B*C*T = 24,576,000
    const int rows     = n / T;                            // 512
    const int nthreads = rows * TPROW;                     // 3,072,000 = 12000*256 exactly
    const int blocks   = nthreads / TPB;                   // 12,000 (48 KB of d_ws)

    // Gaussian window computed on host in double (matches numpy), cast to f32.
    W11 wts;
    double g[11], s = 0.0;
    for (int i = 0; i < 11; i++) { g[i] = exp(-((i - 5) * (i - 5)) / 4.5); s += g[i]; }
    for (int i = 0; i < 11; i++) wts.w[i] = (float)(g[i] / s);

    hipLaunchKernelGGL(ssim_main, dim3(blocks), dim3(TPB), 0, stream,
                       pred, targ, partial, wts);
    hipLaunchKernelGGL(ssim_reduce, dim3(1), dim3(256), 0, stream,
                       (const float4*)partial, blocks / 4, out, 1.0f / (float)n);
}